// Round 1
// baseline (2598.053 us; speedup 1.0000x reference)
//
#include <hip/hip_runtime.h>
#include <math.h>

#define BATCH 64
#define T 256
#define NF 64
#define H 128
#define H4 512                    // 4*H
#define HP1 129
#define WF_STRIDE (HP1 * H4)      // 66048 floats per feature
#define FEATS (NF * H + H)        // 8320
#define NTHREADS 512
#define PACK_UINT4_PER_F 8192     // 16 i * 512 tid (old layout)
#define PACK_BYTES (64u * PACK_UINT4_PER_F * 16u)   // 8 MB

// ---- split-4 path: workspace layout ----
// [flags: 256 int][hbuf: 64*4*2*32 f][cbuf: 64*4*32 f][pack4: 8 MB]
#define NT4 512
#define PACK4_U4_PER_FP 2048      // 4 i * 512 tid per (feature,part)
#define PACK4_BYTES (64u * 4u * PACK4_U4_PER_FP * 16u)  // 8 MB
#define FLAGS_OFF 0
#define HBUF_OFF  8192
#define CBUF_OFF  (HBUF_OFF + 64 * 4 * 2 * 32 * 4)      // 73728
#define PACK4_OFF 131072
#define WS4_NEED  ((size_t)PACK4_OFF + (size_t)PACK4_BYTES)

typedef _Float16 half2_t __attribute__((ext_vector_type(2)));

#define AT_LOADF(p)    __hip_atomic_load((p), __ATOMIC_RELAXED, __HIP_MEMORY_SCOPE_AGENT)
#define AT_STOREF(p,v) __hip_atomic_store((p), (v), __ATOMIC_RELAXED, __HIP_MEMORY_SCOPE_AGENT)

__device__ __forceinline__ float sigmoidf_(float x) {
    return 1.0f / (1.0f + __expf(-x));
}

__device__ __forceinline__ float tanhf_(float x) {
    float ax = fabsf(x);
    float e = __expf(2.0f * ax);              // inf for large ax -> r = 1
    float r = 1.0f - 2.0f / (e + 1.0f);
    return copysignf(r, x);
}

__device__ __forceinline__ float fdot2_(half2_t a, half2_t b, float c) {
#if defined(__has_builtin)
#if __has_builtin(__builtin_amdgcn_fdot2)
    return __builtin_amdgcn_fdot2(a, b, c, false);
#else
    return fmaf((float)a.x, (float)b.x, fmaf((float)a.y, (float)b.y, c));
#endif
#else
    return fmaf((float)a.x, (float)b.x, fmaf((float)a.y, (float)b.y, c));
#endif
}

// ===================== split-4 repack =====================
// pack4[((f*4+p)*4 + i)*512 + tid] : uint4 of 4 half2.
// tid: kq=tid>>7 (K quarter), c=tid&127 (local col), g=c>>5, hh=c&31.
// global col gc = g*128 + p*32 + hh ; k0 = kq*32 + i*8.
// h2[r] = ( W[f][1+k0+2r][gc], W[f][2+k0+2r][gc] ), r=0..3.
__global__ __launch_bounds__(256)
void repack4_kernel(const float* __restrict__ W_lin, uint4* __restrict__ pack) {
    const int lin = blockIdx.x * 256 + threadIdx.x;     // 0..524287
    const int tid = lin & 511;
    const int i   = (lin >> 9) & 3;
    const int p   = (lin >> 11) & 3;
    const int f   = lin >> 13;
    const int kq  = tid >> 7;
    const int c   = tid & 127;
    const int g   = c >> 5;
    const int hh  = c & 31;
    const int gc  = g * 128 + p * 32 + hh;
    const int k0  = kq * 32 + i * 8;
    const float* src = W_lin + (size_t)f * WF_STRIDE + (size_t)(1 + k0) * H4 + gc;
    half2_t h[4];
    #pragma unroll
    for (int r = 0; r < 4; ++r) {
        h[r].x = (_Float16)src[(2 * r) * H4];
        h[r].y = (_Float16)src[(2 * r + 1) * H4];
    }
    pack[lin] = *(uint4*)h;
}

// ===================== split-4 scan =====================
// 4 blocks per batch, block p owns h-lanes [p*32, p*32+32) of all 4 gates.
// Per step: 33 KB fp16 weights/block (vs 132 KB monolithic), h_row chunk
// exchanged via L2 mailboxes with parity double-buffer + monotonic flags.
__global__ __launch_bounds__(NT4, 2)
void lstm_scan_split4(const float* __restrict__ X,
                      const int* __restrict__ lengths,
                      const float* __restrict__ W_lin,
                      const float* __restrict__ b_lin,
                      const float* __restrict__ W_dec,
                      const float* __restrict__ b_dec,
                      const float* __restrict__ W_out,
                      const float* __restrict__ b_out,
                      const uint4* __restrict__ pack,
                      int* __restrict__ flags,
                      float* __restrict__ hbuf,
                      float* __restrict__ cbuf,
                      float* __restrict__ out)
{
    __shared__ float   s_ht[NF * H];      // full h table (32 KB), kept by every block
    __shared__ half2_t s_inp2[H / 2];     // decayed hidden, fp16 pairs
    __shared__ float   s_part[4][128];    // K-split partials for our 128 local cols
    __shared__ float   s_hrow[H];         // this step's full h_row (gathered)
    __shared__ float   s_X[4 * T];
    __shared__ float   s_wdec[NF];
    __shared__ float   s_bdec[NF];
    __shared__ float   s_red[16];
    __shared__ float   s_cfin[H];

    const int tid = threadIdx.x;
    const int bid = blockIdx.x;
    // partners of a batch share bid%8 -> same XCD under round-robin dispatch
    const int xcd = bid & 7;
    const int u   = bid >> 3;             // 0..31
    const int p   = u & 3;                // part 0..3
    const int batch = xcd * 8 + (u >> 2); // 0..63
    const int kq = tid >> 7;              // K quarter
    const int c  = tid & 127;             // local col
    const int gg = c >> 5;
    const int hh = c & 31;
    const int gc = gg * 128 + p * 32 + hh;   // global gate col
    const int me = batch * 4 + p;

    const float* Xb = X + batch * 4 * T;
    const int len = lengths[batch];

    for (int i = tid; i < NF * H; i += NT4) s_ht[i] = 0.0f;
    for (int i = tid; i < 4 * T; i += NT4) s_X[i] = Xb[i];
    if (tid < NF) { s_wdec[tid] = W_dec[tid]; s_bdec[tid] = b_dec[tid]; }
    if (tid < H) ((_Float16*)s_inp2)[tid] = (_Float16)0.0f;
    __syncthreads();

    float c_t = 0.0f, acc = 0.0f, cnt = 0.0f;

    uint4 bufA[4], bufB[4];
    {
        const int m0 = (int)s_X[T];
        const uint4* Wp = pack + ((size_t)(m0 * 4 + p) << 11) + tid;
        #pragma unroll
        for (int i = 0; i < 4; ++i) bufA[i] = Wp[i * 512];
    }

    #define STEP(CUR, NXT)                                                        \
    {                                                                             \
        const int   mj  = (int)s_X[T + j];                                        \
        const float xj  = s_X[2 * T + j];                                         \
        const int   jn  = (j + 1 < T) ? (j + 1) : (T - 1);                        \
        const int   mjn = (int)s_X[T + jn];                                       \
        /* prefetch next step's weights (consumed next iteration) */              \
        {                                                                         \
            const uint4* Wp = pack + ((size_t)(mjn * 4 + p) << 11) + tid;         \
            _Pragma("unroll")                                                     \
            for (int i = 0; i < 4; ++i) NXT[i] = Wp[i * 512];                     \
        }                                                                         \
        float bl0 = 0.0f, bl1 = 0.0f, bl2 = 0.0f, bl3 = 0.0f;                     \
        if (tid < 32) {                                                           \
            const float* bb = b_lin + mj * H4 + p * 32 + tid;                     \
            bl0 = bb[0]; bl1 = bb[128]; bl2 = bb[256]; bl3 = bb[384];             \
        }                                                                         \
        float wx = 0.0f;                                                          \
        if (kq == 0) wx = W_lin[(size_t)mj * WF_STRIDE + gc];                     \
        /* matvec over preloaded registers: 16 fdot2, one local col */            \
        float a = 0.0f;                                                           \
        _Pragma("unroll")                                                         \
        for (int i = 0; i < 4; ++i) {                                             \
            union { uint4 u4; half2_t h[4]; } cv;                                 \
            cv.u4 = CUR[i];                                                       \
            const int ib = kq * 16 + i * 4;                                       \
            a = fdot2_(cv.h[0], s_inp2[ib],     a);                               \
            a = fdot2_(cv.h[1], s_inp2[ib + 1], a);                               \
            a = fdot2_(cv.h[2], s_inp2[ib + 2], a);                               \
            a = fdot2_(cv.h[3], s_inp2[ib + 3], a);                               \
        }                                                                         \
        if (kq == 0) a = fmaf(xj, wx, a);                                         \
        s_part[kq][c] = a;                                                        \
        __syncthreads();  /* B: partials ready */                                 \
        if (tid < 32) {                                                           \
            const float gi = s_part[0][tid]      + s_part[1][tid]      + s_part[2][tid]      + s_part[3][tid]      + bl0; \
            const float gf = s_part[0][32 + tid] + s_part[1][32 + tid] + s_part[2][32 + tid] + s_part[3][32 + tid] + bl1; \
            const float go = s_part[0][64 + tid] + s_part[1][64 + tid] + s_part[2][64 + tid] + s_part[3][64 + tid] + bl2; \
            const float gd = s_part[0][96 + tid] + s_part[1][96 + tid] + s_part[2][96 + tid] + s_part[3][96 + tid] + bl3; \
            const float c_cand = sigmoidf_(gf) * c_t + sigmoidf_(gi) * tanhf_(gd);\
            const float h_row  = sigmoidf_(go) * tanhf_(c_cand);                  \
            acc += c_cand;                                                        \
            cnt += 1.0f;                                                          \
            const float tj = s_X[j];                                              \
            const float tn = (j < T - 1) ? s_X[j + 1] : (tj + 1.0f);              \
            const bool boundary = (j == len - 1) || (tn != tj);                   \
            if (boundary) { c_t = acc / fmaxf(cnt, 1.0f); acc = 0.0f; cnt = 0.0f; } \
            s_hrow[p * 32 + tid] = h_row;                                         \
            AT_STOREF(&hbuf[(size_t)(me * 2 + (j & 1)) * 32 + tid], h_row);       \
        }                                                                         \
        if (tid == 0) {                                                           \
            __builtin_amdgcn_fence(__ATOMIC_RELEASE, "agent");                    \
            AT_STOREF(&flags[me], j + 1);                                         \
        }                                                                         \
        if (tid >= 32 && tid < 128) {                                             \
            const int q  = (tid >> 5) - 1;                                        \
            const int pq = q + (q >= p ? 1 : 0);                                  \
            const int l  = tid & 31;                                              \
            const int fi = batch * 4 + pq;                                        \
            while (AT_LOADF(&flags[fi]) < j + 1) { }                              \
            __builtin_amdgcn_fence(__ATOMIC_ACQUIRE, "agent");                    \
            s_hrow[pq * 32 + l] = AT_LOADF(&hbuf[(size_t)(fi * 2 + (j & 1)) * 32 + l]); \
        }                                                                         \
        __syncthreads();  /* C: full h_row gathered */                            \
        if (tid < H) {                                                            \
            const float v = s_hrow[tid];                                          \
            s_ht[mj * H + tid] = v;                                               \
            const float dn  = s_X[3 * T + jn];                                    \
            const float dmn = fmaf(s_wdec[mjn], dn, s_bdec[mjn]);                 \
            const float den = __expf(-fmaxf(0.0f, dmn));                          \
            const float hv  = (mjn == mj) ? v : s_ht[mjn * H + tid];              \
            ((_Float16*)s_inp2)[tid] = (_Float16)(den * hv);                      \
        }                                                                         \
        __syncthreads();  /* A: s_inp2 + h_t ready */                             \
    }

    int j = 0;
    while (j < len) {
        STEP(bufA, bufB); ++j;
        if (j >= len) break;
        STEP(bufB, bufA); ++j;
    }
    #undef STEP

    // ---- epilogue: gather c_t chunks into block p==0, compute output ----
    if (tid < 32) AT_STOREF(&cbuf[me * 32 + tid], c_t);
    if (tid == 0) {
        __builtin_amdgcn_fence(__ATOMIC_RELEASE, "agent");
        AT_STOREF(&flags[me], len + 1);
    }
    if (p != 0) return;

    if (tid < 32) s_cfin[tid] = c_t;
    if (tid >= 32 && tid < 128) {
        const int q  = (tid >> 5) - 1;
        const int pq = q + 1;                    // p == 0 here
        const int l  = tid & 31;
        const int fi = batch * 4 + pq;
        while (AT_LOADF(&flags[fi]) < len + 1) { }
        __builtin_amdgcn_fence(__ATOMIC_ACQUIRE, "agent");
        s_cfin[pq * 32 + l] = AT_LOADF(&cbuf[fi * 32 + l]);
    }
    __syncthreads();

    float z0 = 0.0f, z1 = 0.0f;
    for (int i = tid; i < FEATS; i += NT4) {
        const float f = (i < H) ? s_cfin[i] : s_ht[i - H];
        const float2 w = *(const float2*)(W_out + 2 * i);
        z0 = fmaf(f, w.x, z0);
        z1 = fmaf(f, w.y, z1);
    }
    #pragma unroll
    for (int off = 32; off > 0; off >>= 1) {
        z0 += __shfl_down(z0, off, 64);
        z1 += __shfl_down(z1, off, 64);
    }
    const int wave = tid >> 6, lane = tid & 63;
    if (lane == 0) { s_red[2 * wave] = z0; s_red[2 * wave + 1] = z1; }
    __syncthreads();
    if (tid == 0) {
        float a0 = b_out[0], a1 = b_out[1];
        #pragma unroll
        for (int w = 0; w < 8; ++w) { a0 += s_red[2 * w]; a1 += s_red[2 * w + 1]; }
        const float mx = fmaxf(a0, a1);
        const float e0 = __expf(a0 - mx), e1 = __expf(a1 - mx);
        const float inv = 1.0f / (e0 + e1);
        out[2 * batch]     = e0 * inv;
        out[2 * batch + 1] = e1 * inv;
    }
}

// ===================== old fp16 path (fallback) =====================
__global__ __launch_bounds__(256)
void repack_kernel(const float* __restrict__ W_lin, uint4* __restrict__ pack) {
    const int lin = blockIdx.x * 256 + threadIdx.x;      // 0..524287
    const int f   = lin >> 13;
    const int i   = (lin >> 9) & 15;
    const int tid = lin & 511;
    const int kq  = tid >> 7;
    const int g4  = tid & 127;
    const int k0  = kq * 32 + 2 * i;
    const float* src = W_lin + (size_t)f * WF_STRIDE + (size_t)(1 + k0) * H4 + 4 * g4;
    const float4 r0 = *(const float4*)(src);
    const float4 r1 = *(const float4*)(src + H4);
    half2_t h[4];
    h[0].x = (_Float16)r0.x; h[0].y = (_Float16)r1.x;
    h[1].x = (_Float16)r0.y; h[1].y = (_Float16)r1.y;
    h[2].x = (_Float16)r0.z; h[2].y = (_Float16)r1.z;
    h[3].x = (_Float16)r0.w; h[3].y = (_Float16)r1.w;
    pack[lin] = *(uint4*)h;
}

__global__ __launch_bounds__(NTHREADS, 2)
void lstm_scan_fp16_kernel(const float* __restrict__ X,
                           const int* __restrict__ lengths,
                           const float* __restrict__ W_lin,
                           const float* __restrict__ b_lin,
                           const float* __restrict__ W_dec,
                           const float* __restrict__ b_dec,
                           const float* __restrict__ W_out,
                           const float* __restrict__ b_out,
                           const uint4* __restrict__ pack,
                           float* __restrict__ out)
{
    __shared__ float s_feats[FEATS];
    __shared__ half2_t s_inp2[H / 2];
    __shared__ float s_part[4][H4];
    __shared__ float s_X[4 * T];
    __shared__ float s_wdec[NF];
    __shared__ float s_bdec[NF];
    __shared__ float s_red[16];

    float* s_ct = s_feats;
    float* s_ht = s_feats + H;

    const int tid = threadIdx.x;
    const int b   = blockIdx.x;
    const int g4  = tid & 127;
    const int kq  = tid >> 7;

    const float* Xb = X + b * 4 * T;
    const int len = lengths[b];

    for (int i = tid; i < NF * H; i += NTHREADS) s_ht[i] = 0.0f;
    for (int i = tid; i < 4 * T; i += NTHREADS) s_X[i] = Xb[i];
    if (tid < NF) { s_wdec[tid] = W_dec[tid]; s_bdec[tid] = b_dec[tid]; }
    if (tid < H / 2) { half2_t z; z.x = (_Float16)0.0f; z.y = (_Float16)0.0f; s_inp2[tid] = z; }
    __syncthreads();

    float c_t = 0.0f, acc = 0.0f, cnt = 0.0f;

    uint4 bufA[16], bufB[16];
    {
        const int m0 = (int)s_X[T];
        const uint4* Wp = pack + m0 * PACK_UINT4_PER_F + tid;
        #pragma unroll
        for (int i = 0; i < 16; ++i) bufA[i] = Wp[i * 512];
    }

    #define STEP(CUR, NXT)                                                          \
    {                                                                               \
        const int   mj = (int)s_X[T + j];                                           \
        const float xj = s_X[2 * T + j];                                            \
        const int   jn = (j + 1 < T) ? (j + 1) : (T - 1);                           \
        const int   mjn = (int)s_X[T + jn];                                         \
        {                                                                           \
            const uint4* Wp = pack + mjn * PACK_UINT4_PER_F + tid;                  \
            _Pragma("unroll")                                                       \
            for (int i = 0; i < 16; ++i) NXT[i] = Wp[i * 512];                      \
        }                                                                           \
        float bl0, bl1, bl2, bl3;                                                   \
        if (tid < H) {                                                              \
            const int m4 = mj * H4;                                                 \
            bl0 = b_lin[m4 + tid];                                                  \
            bl1 = b_lin[m4 + H + tid];                                              \
            bl2 = b_lin[m4 + 2 * H + tid];                                          \
            bl3 = b_lin[m4 + 3 * H + tid];                                          \
        }                                                                           \
        float a0 = 0.0f, a1 = 0.0f, a2 = 0.0f, a3 = 0.0f;                           \
        _Pragma("unroll")                                                           \
        for (int i = 0; i < 16; ++i) {                                              \
            union { uint4 u; half2_t h[4]; } cv;                                    \
            cv.u = CUR[i];                                                          \
            const half2_t iv = s_inp2[kq * 16 + i];                                 \
            a0 = fdot2_(cv.h[0], iv, a0);                                           \
            a1 = fdot2_(cv.h[1], iv, a1);                                           \
            a2 = fdot2_(cv.h[2], iv, a2);                                           \
            a3 = fdot2_(cv.h[3], iv, a3);                                           \
        }                                                                           \
        if (kq == 0) {                                                              \
            const float4 w = *(const float4*)(W_lin + (size_t)mj * WF_STRIDE + 4 * g4); \
            a0 = fmaf(xj, w.x, a0); a1 = fmaf(xj, w.y, a1);                         \
            a2 = fmaf(xj, w.z, a2); a3 = fmaf(xj, w.w, a3);                         \
        }                                                                           \
        float4 a4; a4.x = a0; a4.y = a1; a4.z = a2; a4.w = a3;                      \
        *(float4*)(&s_part[kq][4 * g4]) = a4;                                       \
        __syncthreads();                                                            \
        if (tid < H) {                                                              \
            const int h = tid;                                                      \
            const float gi = s_part[0][h]         + s_part[1][h]         + s_part[2][h]         + s_part[3][h]         + bl0; \
            const float gf = s_part[0][H + h]     + s_part[1][H + h]     + s_part[2][H + h]     + s_part[3][H + h]     + bl1; \
            const float go = s_part[0][2*H + h]   + s_part[1][2*H + h]   + s_part[2][2*H + h]   + s_part[3][2*H + h]   + bl2; \
            const float gc = s_part[0][3*H + h]   + s_part[1][3*H + h]   + s_part[2][3*H + h]   + s_part[3][3*H + h]   + bl3; \
            const float c_cand = sigmoidf_(gf) * c_t + sigmoidf_(gi) * tanhf_(gc);  \
            const float h_row  = sigmoidf_(go) * tanhf_(c_cand);                    \
            s_ht[mj * H + h] = h_row;                                               \
            acc += c_cand;                                                          \
            cnt += 1.0f;                                                            \
            const float tj = s_X[j];                                                \
            const float tn = (j < T - 1) ? s_X[j + 1] : (tj + 1.0f);                \
            const bool boundary = (j == len - 1) || (tn != tj);                     \
            if (boundary) { c_t = acc / fmaxf(cnt, 1.0f); acc = 0.0f; cnt = 0.0f; } \
            const float dn  = s_X[3 * T + jn];                                      \
            const float dmn = fmaf(s_wdec[mjn], dn, s_bdec[mjn]);                   \
            const float den = __expf(-fmaxf(0.0f, dmn));                            \
            const float hv  = (mjn == mj) ? h_row : s_ht[mjn * H + h];              \
            ((_Float16*)s_inp2)[h] = (_Float16)(den * hv);                          \
        }                                                                           \
        __syncthreads();                                                            \
    }

    int j = 0;
    while (j < len) {
        STEP(bufA, bufB); ++j;
        if (j >= len) break;
        STEP(bufB, bufA); ++j;
    }
    #undef STEP

    if (tid < H) s_ct[tid] = c_t;
    __syncthreads();

    float z0 = 0.0f, z1 = 0.0f;
    for (int i = tid; i < FEATS; i += NTHREADS) {
        const float f = s_feats[i];
        const float2 w = *(const float2*)(W_out + 2 * i);
        z0 = fmaf(f, w.x, z0);
        z1 = fmaf(f, w.y, z1);
    }
    #pragma unroll
    for (int off = 32; off > 0; off >>= 1) {
        z0 += __shfl_down(z0, off, 64);
        z1 += __shfl_down(z1, off, 64);
    }
    const int wave = tid >> 6, lane = tid & 63;
    if (lane == 0) { s_red[2 * wave] = z0; s_red[2 * wave + 1] = z1; }
    __syncthreads();
    if (tid == 0) {
        float a0 = b_out[0], a1 = b_out[1];
        #pragma unroll
        for (int w = 0; w < 8; ++w) { a0 += s_red[2 * w]; a1 += s_red[2 * w + 1]; }
        const float mx = fmaxf(a0, a1);
        const float e0 = __expf(a0 - mx), e1 = __expf(a1 - mx);
        const float inv = 1.0f / (e0 + e1);
        out[2 * b]     = e0 * inv;
        out[2 * b + 1] = e1 * inv;
    }
}

// ---------------- fp32 fallback ----------------
__global__ __launch_bounds__(NTHREADS)
void lstm_scan_kernel(const float* __restrict__ X,
                      const int* __restrict__ lengths,
                      const float* __restrict__ W_lin,
                      const float* __restrict__ b_lin,
                      const float* __restrict__ W_dec,
                      const float* __restrict__ b_dec,
                      const float* __restrict__ W_out,
                      const float* __restrict__ b_out,
                      float* __restrict__ out)
{
    __shared__ float s_feats[FEATS];
    __shared__ float s_inp[H];
    __shared__ float s_part[4][H4];
    __shared__ float s_X[4 * T];
    __shared__ float s_wdec[NF];
    __shared__ float s_bdec[NF];
    __shared__ float s_red[16];

    float* s_ct = s_feats;
    float* s_ht = s_feats + H;

    const int tid = threadIdx.x;
    const int b   = blockIdx.x;
    const int g4  = tid & 127;
    const int kq  = tid >> 7;

    const float* Xb = X + b * 4 * T;
    const int len = lengths[b];

    for (int i = tid; i < NF * H; i += NTHREADS) s_ht[i] = 0.0f;
    for (int i = tid; i < 4 * T; i += NTHREADS) s_X[i] = Xb[i];
    if (tid < NF) { s_wdec[tid] = W_dec[tid]; s_bdec[tid] = b_dec[tid]; }
    __syncthreads();

    float c_t = 0.0f, acc = 0.0f, cnt = 0.0f;

    for (int j = 0; j < len; ++j) {
        const int   mj = (int)s_X[T + j];
        const float xj = s_X[2 * T + j];
        const float* Wf = W_lin + mj * WF_STRIDE;

        float bl0, bl1, bl2, bl3;
        if (tid < H) {
            const float dj    = s_X[3 * T + j];
            const float dm    = fmaf(s_wdec[mj], dj, s_bdec[mj]);
            const float decay = __expf(-fmaxf(0.0f, dm));
            s_inp[tid] = decay * s_ht[mj * H + tid];
            const int m4 = mj * H4;
            bl0 = b_lin[m4 + tid];
            bl1 = b_lin[m4 + H + tid];
            bl2 = b_lin[m4 + 2 * H + tid];
            bl3 = b_lin[m4 + 3 * H + tid];
        }
        __syncthreads();

        float4 a4 = make_float4(0.0f, 0.0f, 0.0f, 0.0f);
        {
            const float*  wr  = Wf + (1 + kq * 32) * H4 + 4 * g4;
            const float4* ivp = (const float4*)(s_inp + kq * 32);
            #pragma unroll
            for (int c = 0; c < 8; ++c) {
                const float4 v = ivp[c];
                const float* wrc = wr + (4 * c) * H4;
                const float4 w0 = *(const float4*)(wrc);
                const float4 w1 = *(const float4*)(wrc + H4);
                const float4 w2 = *(const float4*)(wrc + 2 * H4);
                const float4 w3 = *(const float4*)(wrc + 3 * H4);
                a4.x = fmaf(v.x, w0.x, a4.x); a4.y = fmaf(v.x, w0.y, a4.y);
                a4.z = fmaf(v.x, w0.z, a4.z); a4.w = fmaf(v.x, w0.w, a4.w);
                a4.x = fmaf(v.y, w1.x, a4.x); a4.y = fmaf(v.y, w1.y, a4.y);
                a4.z = fmaf(v.y, w1.z, a4.z); a4.w = fmaf(v.y, w1.w, a4.w);
                a4.x = fmaf(v.z, w2.x, a4.x); a4.y = fmaf(v.z, w2.y, a4.y);
                a4.z = fmaf(v.z, w2.z, a4.z); a4.w = fmaf(v.z, w2.w, a4.w);
                a4.x = fmaf(v.w, w3.x, a4.x); a4.y = fmaf(v.w, w3.y, a4.y);
                a4.z = fmaf(v.w, w3.z, a4.z); a4.w = fmaf(v.w, w3.w, a4.w);
            }
        }
        if (kq == 0) {
            const float4 w = *(const float4*)(Wf + 4 * g4);
            a4.x = fmaf(xj, w.x, a4.x); a4.y = fmaf(xj, w.y, a4.y);
            a4.z = fmaf(xj, w.z, a4.z); a4.w = fmaf(xj, w.w, a4.w);
        }
        *(float4*)(&s_part[kq][4 * g4]) = a4;
        __syncthreads();

        if (tid < H) {
            const int h = tid;
            const float gi = s_part[0][h]         + s_part[1][h]         + s_part[2][h]         + s_part[3][h]         + bl0;
            const float gf = s_part[0][H + h]     + s_part[1][H + h]     + s_part[2][H + h]     + s_part[3][H + h]     + bl1;
            const float go = s_part[0][2*H + h]   + s_part[1][2*H + h]   + s_part[2][2*H + h]   + s_part[3][2*H + h]   + bl2;
            const float gc = s_part[0][3*H + h]   + s_part[1][3*H + h]   + s_part[2][3*H + h]   + s_part[3][3*H + h]   + bl3;

            const float c_cand = sigmoidf_(gf) * c_t + sigmoidf_(gi) * tanhf_(gc);
            const float h_row  = sigmoidf_(go) * tanhf_(c_cand);
            s_ht[mj * H + h] = h_row;
            acc += c_cand;
            cnt += 1.0f;

            const float tj = s_X[j];
            const float tn = (j < T - 1) ? s_X[j + 1] : (tj + 1.0f);
            const bool boundary = (j == len - 1) || (tn != tj);
            if (boundary) { c_t = acc / fmaxf(cnt, 1.0f); acc = 0.0f; cnt = 0.0f; }
        }
        __syncthreads();
    }

    if (tid < H) s_ct[tid] = c_t;
    __syncthreads();

    float z0 = 0.0f, z1 = 0.0f;
    for (int i = tid; i < FEATS; i += NTHREADS) {
        const float f = s_feats[i];
        const float2 w = *(const float2*)(W_out + 2 * i);
        z0 = fmaf(f, w.x, z0);
        z1 = fmaf(f, w.y, z1);
    }
    #pragma unroll
    for (int off = 32; off > 0; off >>= 1) {
        z0 += __shfl_down(z0, off, 64);
        z1 += __shfl_down(z1, off, 64);
    }
    const int wave = tid >> 6, lane = tid & 63;
    if (lane == 0) { s_red[2 * wave] = z0; s_red[2 * wave + 1] = z1; }
    __syncthreads();
    if (tid == 0) {
        float a0 = b_out[0], a1 = b_out[1];
        #pragma unroll
        for (int w = 0; w < 8; ++w) { a0 += s_red[2 * w]; a1 += s_red[2 * w + 1]; }
        const float mx = fmaxf(a0, a1);
        const float e0 = __expf(a0 - mx), e1 = __expf(a1 - mx);
        const float inv = 1.0f / (e0 + e1);
        out[2 * b]     = e0 * inv;
        out[2 * b + 1] = e1 * inv;
    }
}

extern "C" void kernel_launch(void* const* d_in, const int* in_sizes, int n_in,
                              void* d_out, int out_size, void* d_ws, size_t ws_size,
                              hipStream_t stream) {
    const float* X      = (const float*)d_in[0];
    const int*   lens   = (const int*)d_in[1];
    const float* W_lin  = (const float*)d_in[2];
    const float* b_lin  = (const float*)d_in[3];
    const float* W_dec  = (const float*)d_in[4];
    const float* b_dec  = (const float*)d_in[5];
    const float* W_out  = (const float*)d_in[6];
    const float* b_out  = (const float*)d_in[7];
    float* out = (float*)d_out;

    if (ws_size >= WS4_NEED) {
        char*  ws    = (char*)d_ws;
        int*   flags = (int*)(ws + FLAGS_OFF);
        float* hbuf  = (float*)(ws + HBUF_OFF);
        float* cbuf  = (float*)(ws + CBUF_OFF);
        uint4* pack  = (uint4*)(ws + PACK4_OFF);
        hipMemsetAsync(flags, 0, 256 * sizeof(int), stream);
        hipLaunchKernelGGL(repack4_kernel, dim3(2048), dim3(256), 0, stream, W_lin, pack);
        hipLaunchKernelGGL(lstm_scan_split4, dim3(4 * BATCH), dim3(NT4), 0, stream,
                           X, lens, W_lin, b_lin, W_dec, b_dec, W_out, b_out,
                           pack, flags, hbuf, cbuf, out);
    } else if (ws_size >= (size_t)PACK_BYTES) {
        uint4* pack = (uint4*)d_ws;
        hipLaunchKernelGGL(repack_kernel, dim3(2048), dim3(256), 0, stream, W_lin, pack);
        hipLaunchKernelGGL(lstm_scan_fp16_kernel, dim3(BATCH), dim3(NTHREADS), 0, stream,
                           X, lens, W_lin, b_lin, W_dec, b_dec, W_out, b_out, pack, out);
    } else {
        hipLaunchKernelGGL(lstm_scan_kernel, dim3(BATCH), dim3(NTHREADS), 0, stream,
                           X, lens, W_lin, b_lin, W_dec, b_dec, W_out, b_out, out);
    }
}

// Round 2
// 525.365 us; speedup vs baseline: 4.9452x; 4.9452x over previous
//
#include <hip/hip_runtime.h>
#include <math.h>

#define BATCH 64
#define T 256
#define NF 64
#define H 128
#define H4 512                    // 4*H
#define HP1 129
#define WF_STRIDE (HP1 * H4)      // 66048 floats per feature
#define FEATS (NF * H + H)        // 8320
#define NTHREADS 512
#define PACK_UINT4_PER_F 8192     // 16 i * 512 tid
#define PACK_BYTES (64u * PACK_UINT4_PER_F * 16u)   // 8 MB

typedef _Float16 half2_t __attribute__((ext_vector_type(2)));

__device__ __forceinline__ float sigmoidf_(float x) {
    return 1.0f / (1.0f + __expf(-x));
}

__device__ __forceinline__ float tanhf_(float x) {
    float ax = fabsf(x);
    float e = __expf(2.0f * ax);              // inf for large ax -> r = 1
    float r = 1.0f - 2.0f / (e + 1.0f);
    return copysignf(r, x);
}

__device__ __forceinline__ float fdot2_(half2_t a, half2_t b, float c) {
#if defined(__has_builtin)
#if __has_builtin(__builtin_amdgcn_fdot2)
    return __builtin_amdgcn_fdot2(a, b, c, false);
#else
    return fmaf((float)a.x, (float)b.x, fmaf((float)a.y, (float)b.y, c));
#endif
#else
    return fmaf((float)a.x, (float)b.x, fmaf((float)a.y, (float)b.y, c));
#endif
}

// ---------------- repack: W_lin rows 1..128 (h-part) -> fp16 blocked layout ----
// pack[(f*16 + i)*512 + tid] = uint4 of 4 half2:
//   for g in 0..3: ( W[f][1+k0][4*g4+g], W[f][2+k0][4*g4+g] )
//   where kq = tid>>7, g4 = tid&127, k0 = kq*32 + 2*i
__global__ __launch_bounds__(256)
void repack_kernel(const float* __restrict__ W_lin, uint4* __restrict__ pack) {
    const int lin = blockIdx.x * 256 + threadIdx.x;      // 0..524287
    const int f   = lin >> 13;
    const int i   = (lin >> 9) & 15;
    const int tid = lin & 511;
    const int kq  = tid >> 7;
    const int g4  = tid & 127;
    const int k0  = kq * 32 + 2 * i;
    const float* src = W_lin + (size_t)f * WF_STRIDE + (size_t)(1 + k0) * H4 + 4 * g4;
    const float4 r0 = *(const float4*)(src);
    const float4 r1 = *(const float4*)(src + H4);
    half2_t h[4];
    h[0].x = (_Float16)r0.x; h[0].y = (_Float16)r1.x;
    h[1].x = (_Float16)r0.y; h[1].y = (_Float16)r1.y;
    h[2].x = (_Float16)r0.z; h[2].y = (_Float16)r1.z;
    h[3].x = (_Float16)r0.w; h[3].y = (_Float16)r1.w;
    pack[lin] = *(uint4*)h;
}

// ---------------- main scan kernel (fp16 weights, full register pipeline) ----
// Key change vs previous best: bias (b_lin) and the x-row (W_lin row 0) are
// prefetched ONE STEP AHEAD into registers, exactly like the weight buffers.
// Previously both were loaded AND consumed inside the same step, forcing an
// s_waitcnt vmcnt(0) in waves 0-1 that drained the 16-load weight prefetch
// every step (step ~= stream + compute instead of max(stream, compute)).
__global__ __launch_bounds__(NTHREADS, 2)
void lstm_scan_fp16_kernel(const float* __restrict__ X,
                           const int* __restrict__ lengths,
                           const float* __restrict__ W_lin,
                           const float* __restrict__ b_lin,
                           const float* __restrict__ W_dec,
                           const float* __restrict__ b_dec,
                           const float* __restrict__ W_out,
                           const float* __restrict__ b_out,
                           const uint4* __restrict__ pack,
                           float* __restrict__ out)
{
    __shared__ float s_feats[FEATS];          // [0,H)=c_t, [H,..)=h_t row-major
    __shared__ half2_t s_inp2[H / 2];         // decayed hidden row, fp16 pairs
    __shared__ float s_part[4][H4];           // K-split matvec partials
    __shared__ float s_X[4 * T];
    __shared__ float s_wdec[NF];
    __shared__ float s_bdec[NF];
    __shared__ float s_red[16];

    float* s_ct = s_feats;
    float* s_ht = s_feats + H;

    const int tid = threadIdx.x;
    const int b   = blockIdx.x;
    const int g4  = tid & 127;
    const int kq  = tid >> 7;

    const float* Xb = X + b * 4 * T;
    const int len = lengths[b];

    for (int i = tid; i < NF * H; i += NTHREADS) s_ht[i] = 0.0f;
    for (int i = tid; i < 4 * T; i += NTHREADS) s_X[i] = Xb[i];
    if (tid < NF) { s_wdec[tid] = W_dec[tid]; s_bdec[tid] = b_dec[tid]; }
    if (tid < H / 2) { half2_t z; z.x = (_Float16)0.0f; z.y = (_Float16)0.0f; s_inp2[tid] = z; }
    __syncthreads();

    float c_t = 0.0f, acc = 0.0f, cnt = 0.0f;

    uint4 bufA[16], bufB[16];
    float4 blA = make_float4(0.f, 0.f, 0.f, 0.f), blB = make_float4(0.f, 0.f, 0.f, 0.f);
    float4 wxA = make_float4(0.f, 0.f, 0.f, 0.f), wxB = make_float4(0.f, 0.f, 0.f, 0.f);

    // prologue prefetch for step 0
    {
        const int m0 = (int)s_X[T];
        const uint4* Wp = pack + m0 * PACK_UINT4_PER_F + tid;
        #pragma unroll
        for (int i = 0; i < 16; ++i) bufA[i] = Wp[i * 512];
        if (tid < H) {
            const float* bb = b_lin + m0 * H4 + tid;
            blA.x = bb[0]; blA.y = bb[H]; blA.z = bb[2 * H]; blA.w = bb[3 * H];
        }
        if (kq == 0) wxA = *(const float4*)(W_lin + (size_t)m0 * WF_STRIDE + 4 * g4);
    }

    #define STEP(CURW, NXTW, CURB, NXTB, CURX, NXTX)                                \
    {                                                                               \
        const int   mj = (int)s_X[T + j];                                           \
        const float xj = s_X[2 * T + j];                                            \
        const int   jn = (j + 1 < T) ? (j + 1) : (T - 1);                           \
        const int   mjn = (int)s_X[T + jn];                                         \
        /* prefetch next step's weights / bias / x-row (consumed NEXT step) */      \
        {                                                                           \
            const uint4* Wp = pack + mjn * PACK_UINT4_PER_F + tid;                  \
            _Pragma("unroll")                                                       \
            for (int i = 0; i < 16; ++i) NXTW[i] = Wp[i * 512];                     \
        }                                                                           \
        if (tid < H) {                                                              \
            const float* bb = b_lin + mjn * H4 + tid;                               \
            NXTB.x = bb[0]; NXTB.y = bb[H]; NXTB.z = bb[2 * H]; NXTB.w = bb[3 * H]; \
        }                                                                           \
        if (kq == 0) NXTX = *(const float4*)(W_lin + (size_t)mjn * WF_STRIDE + 4 * g4); \
        /* matvec over registers preloaded LAST step */                             \
        float a0 = 0.0f, a1 = 0.0f, a2 = 0.0f, a3 = 0.0f;                           \
        _Pragma("unroll")                                                           \
        for (int i = 0; i < 16; ++i) {                                              \
            union { uint4 u; half2_t h[4]; } cv;                                    \
            cv.u = CURW[i];                                                         \
            const half2_t iv = s_inp2[kq * 16 + i];                                 \
            a0 = fdot2_(cv.h[0], iv, a0);                                           \
            a1 = fdot2_(cv.h[1], iv, a1);                                           \
            a2 = fdot2_(cv.h[2], iv, a2);                                           \
            a3 = fdot2_(cv.h[3], iv, a3);                                           \
        }                                                                           \
        if (kq == 0) {                                                              \
            a0 = fmaf(xj, CURX.x, a0); a1 = fmaf(xj, CURX.y, a1);                   \
            a2 = fmaf(xj, CURX.z, a2); a3 = fmaf(xj, CURX.w, a3);                   \
        }                                                                           \
        float4 a4; a4.x = a0; a4.y = a1; a4.z = a2; a4.w = a3;                      \
        *(float4*)(&s_part[kq][4 * g4]) = a4;                                       \
        __syncthreads();  /* B: partials ready */                                   \
        if (tid < H) {                                                              \
            const int h = tid;                                                      \
            const float gi = s_part[0][h]         + s_part[1][h]         + s_part[2][h]         + s_part[3][h]         + CURB.x; \
            const float gf = s_part[0][H + h]     + s_part[1][H + h]     + s_part[2][H + h]     + s_part[3][H + h]     + CURB.y; \
            const float go = s_part[0][2*H + h]   + s_part[1][2*H + h]   + s_part[2][2*H + h]   + s_part[3][2*H + h]   + CURB.z; \
            const float gc = s_part[0][3*H + h]   + s_part[1][3*H + h]   + s_part[2][3*H + h]   + s_part[3][3*H + h]   + CURB.w; \
            const float c_cand = sigmoidf_(gf) * c_t + sigmoidf_(gi) * tanhf_(gc);  \
            const float h_row  = sigmoidf_(go) * tanhf_(c_cand);                    \
            s_ht[mj * H + h] = h_row;                                               \
            acc += c_cand;                                                          \
            cnt += 1.0f;                                                            \
            const float tj = s_X[j];                                                \
            const float tn = (j < T - 1) ? s_X[j + 1] : (tj + 1.0f);                \
            const bool boundary = (j == len - 1) || (tn != tj);                     \
            if (boundary) { c_t = acc / fmaxf(cnt, 1.0f); acc = 0.0f; cnt = 0.0f; } \
            /* produce next step's decayed input (fp16) */                          \
            const float dn  = s_X[3 * T + jn];                                      \
            const float dmn = fmaf(s_wdec[mjn], dn, s_bdec[mjn]);                   \
            const float den = __expf(-fmaxf(0.0f, dmn));                            \
            const float hv  = (mjn == mj) ? h_row : s_ht[mjn * H + h];              \
            ((_Float16*)s_inp2)[h] = (_Float16)(den * hv);                          \
        }                                                                           \
        __syncthreads();  /* A: s_inp2 + h_t ready */                               \
    }

    int j = 0;
    while (j < len) {
        STEP(bufA, bufB, blA, blB, wxA, wxB); ++j;
        if (j >= len) break;
        STEP(bufB, bufA, blB, blA, wxB, wxA); ++j;
    }
    #undef STEP

    // ---- epilogue ----
    if (tid < H) s_ct[tid] = c_t;
    __syncthreads();

    float z0 = 0.0f, z1 = 0.0f;
    for (int i = tid; i < FEATS; i += NTHREADS) {
        const float f = s_feats[i];
        const float2 w = *(const float2*)(W_out + 2 * i);
        z0 = fmaf(f, w.x, z0);
        z1 = fmaf(f, w.y, z1);
    }
    #pragma unroll
    for (int off = 32; off > 0; off >>= 1) {
        z0 += __shfl_down(z0, off, 64);
        z1 += __shfl_down(z1, off, 64);
    }
    const int wave = tid >> 6, lane = tid & 63;
    if (lane == 0) { s_red[2 * wave] = z0; s_red[2 * wave + 1] = z1; }
    __syncthreads();
    if (tid == 0) {
        float a0 = b_out[0], a1 = b_out[1];
        #pragma unroll
        for (int w = 0; w < 8; ++w) { a0 += s_red[2 * w]; a1 += s_red[2 * w + 1]; }
        const float mx = fmaxf(a0, a1);
        const float e0 = __expf(a0 - mx), e1 = __expf(a1 - mx);
        const float inv = 1.0f / (e0 + e1);
        out[2 * b]     = e0 * inv;
        out[2 * b + 1] = e1 * inv;
    }
}

// ---------------- fp32 fallback (no-workspace path) ----------------
__global__ __launch_bounds__(NTHREADS)
void lstm_scan_kernel(const float* __restrict__ X,
                      const int* __restrict__ lengths,
                      const float* __restrict__ W_lin,
                      const float* __restrict__ b_lin,
                      const float* __restrict__ W_dec,
                      const float* __restrict__ b_dec,
                      const float* __restrict__ W_out,
                      const float* __restrict__ b_out,
                      float* __restrict__ out)
{
    __shared__ float s_feats[FEATS];
    __shared__ float s_inp[H];
    __shared__ float s_part[4][H4];
    __shared__ float s_X[4 * T];
    __shared__ float s_wdec[NF];
    __shared__ float s_bdec[NF];
    __shared__ float s_red[16];

    float* s_ct = s_feats;
    float* s_ht = s_feats + H;

    const int tid = threadIdx.x;
    const int b   = blockIdx.x;
    const int g4  = tid & 127;
    const int kq  = tid >> 7;

    const float* Xb = X + b * 4 * T;
    const int len = lengths[b];

    for (int i = tid; i < NF * H; i += NTHREADS) s_ht[i] = 0.0f;
    for (int i = tid; i < 4 * T; i += NTHREADS) s_X[i] = Xb[i];
    if (tid < NF) { s_wdec[tid] = W_dec[tid]; s_bdec[tid] = b_dec[tid]; }
    __syncthreads();

    float c_t = 0.0f, acc = 0.0f, cnt = 0.0f;

    for (int j = 0; j < len; ++j) {
        const int   mj = (int)s_X[T + j];
        const float xj = s_X[2 * T + j];
        const float* Wf = W_lin + mj * WF_STRIDE;

        float bl0, bl1, bl2, bl3;
        if (tid < H) {
            const float dj    = s_X[3 * T + j];
            const float dm    = fmaf(s_wdec[mj], dj, s_bdec[mj]);
            const float decay = __expf(-fmaxf(0.0f, dm));
            s_inp[tid] = decay * s_ht[mj * H + tid];
            const int m4 = mj * H4;
            bl0 = b_lin[m4 + tid];
            bl1 = b_lin[m4 + H + tid];
            bl2 = b_lin[m4 + 2 * H + tid];
            bl3 = b_lin[m4 + 3 * H + tid];
        }
        __syncthreads();

        float4 a4 = make_float4(0.0f, 0.0f, 0.0f, 0.0f);
        {
            const float*  wr  = Wf + (1 + kq * 32) * H4 + 4 * g4;
            const float4* ivp = (const float4*)(s_inp + kq * 32);
            #pragma unroll
            for (int c = 0; c < 8; ++c) {
                const float4 v = ivp[c];
                const float* wrc = wr + (4 * c) * H4;
                const float4 w0 = *(const float4*)(wrc);
                const float4 w1 = *(const float4*)(wrc + H4);
                const float4 w2 = *(const float4*)(wrc + 2 * H4);
                const float4 w3 = *(const float4*)(wrc + 3 * H4);
                a4.x = fmaf(v.x, w0.x, a4.x); a4.y = fmaf(v.x, w0.y, a4.y);
                a4.z = fmaf(v.x, w0.z, a4.z); a4.w = fmaf(v.x, w0.w, a4.w);
                a4.x = fmaf(v.y, w1.x, a4.x); a4.y = fmaf(v.y, w1.y, a4.y);
                a4.z = fmaf(v.y, w1.z, a4.z); a4.w = fmaf(v.y, w1.w, a4.w);
                a4.x = fmaf(v.z, w2.x, a4.x); a4.y = fmaf(v.z, w2.y, a4.y);
                a4.z = fmaf(v.z, w2.z, a4.z); a4.w = fmaf(v.z, w2.w, a4.w);
                a4.x = fmaf(v.w, w3.x, a4.x); a4.y = fmaf(v.w, w3.y, a4.y);
                a4.z = fmaf(v.w, w3.z, a4.z); a4.w = fmaf(v.w, w3.w, a4.w);
            }
        }
        if (kq == 0) {
            const float4 w = *(const float4*)(Wf + 4 * g4);
            a4.x = fmaf(xj, w.x, a4.x); a4.y = fmaf(xj, w.y, a4.y);
            a4.z = fmaf(xj, w.z, a4.z); a4.w = fmaf(xj, w.w, a4.w);
        }
        *(float4*)(&s_part[kq][4 * g4]) = a4;
        __syncthreads();

        if (tid < H) {
            const int h = tid;
            const float gi = s_part[0][h]         + s_part[1][h]         + s_part[2][h]         + s_part[3][h]         + bl0;
            const float gf = s_part[0][H + h]     + s_part[1][H + h]     + s_part[2][H + h]     + s_part[3][H + h]     + bl1;
            const float go = s_part[0][2*H + h]   + s_part[1][2*H + h]   + s_part[2][2*H + h]   + s_part[3][2*H + h]   + bl2;
            const float gc = s_part[0][3*H + h]   + s_part[1][3*H + h]   + s_part[2][3*H + h]   + s_part[3][3*H + h]   + bl3;

            const float c_cand = sigmoidf_(gf) * c_t + sigmoidf_(gi) * tanhf_(gc);
            const float h_row  = sigmoidf_(go) * tanhf_(c_cand);
            s_ht[mj * H + h] = h_row;
            acc += c_cand;
            cnt += 1.0f;

            const float tj = s_X[j];
            const float tn = (j < T - 1) ? s_X[j + 1] : (tj + 1.0f);
            const bool boundary = (j == len - 1) || (tn != tj);
            if (boundary) { c_t = acc / fmaxf(cnt, 1.0f); acc = 0.0f; cnt = 0.0f; }
        }
        __syncthreads();
    }

    if (tid < H) s_ct[tid] = c_t;
    __syncthreads();

    float z0 = 0.0f, z1 = 0.0f;
    for (int i = tid; i < FEATS; i += NTHREADS) {
        const float f = s_feats[i];
        const float2 w = *(const float2*)(W_out + 2 * i);
        z0 = fmaf(f, w.x, z0);
        z1 = fmaf(f, w.y, z1);
    }
    #pragma unroll
    for (int off = 32; off > 0; off >>= 1) {
        z0 += __shfl_down(z0, off, 64);
        z1 += __shfl_down(z1, off, 64);
    }
    const int wave = tid >> 6, lane = tid & 63;
    if (lane == 0) { s_red[2 * wave] = z0; s_red[2 * wave + 1] = z1; }
    __syncthreads();
    if (tid == 0) {
        float a0 = b_out[0], a1 = b_out[1];
        #pragma unroll
        for (int w = 0; w < 8; ++w) { a0 += s_red[2 * w]; a1 += s_red[2 * w + 1]; }
        const float mx = fmaxf(a0, a1);
        const float e0 = __expf(a0 - mx), e1 = __expf(a1 - mx);
        const float inv = 1.0f / (e0 + e1);
        out[2 * b]     = e0 * inv;
        out[2 * b + 1] = e1 * inv;
    }
}

extern "C" void kernel_launch(void* const* d_in, const int* in_sizes, int n_in,
                              void* d_out, int out_size, void* d_ws, size_t ws_size,
                              hipStream_t stream) {
    const float* X      = (const float*)d_in[0];
    const int*   lens   = (const int*)d_in[1];
    const float* W_lin  = (const float*)d_in[2];
    const float* b_lin  = (const float*)d_in[3];
    const float* W_dec  = (const float*)d_in[4];
    const float* b_dec  = (const float*)d_in[5];
    const float* W_out  = (const float*)d_in[6];
    const float* b_out  = (const float*)d_in[7];
    float* out = (float*)d_out;

    if (ws_size >= (size_t)PACK_BYTES) {
        uint4* pack = (uint4*)d_ws;
        hipLaunchKernelGGL(repack_kernel, dim3(2048), dim3(256), 0, stream, W_lin, pack);
        hipLaunchKernelGGL(lstm_scan_fp16_kernel, dim3(BATCH), dim3(NTHREADS), 0, stream,
                           X, lens, W_lin, b_lin, W_dec, b_dec, W_out, b_out, pack, out);
    } else {
        hipLaunchKernelGGL(lstm_scan_kernel, dim3(BATCH), dim3(NTHREADS), 0, stream,
                           X, lens, W_lin, b_lin, W_dec, b_dec, W_out, b_out, out);
    }
}

// Round 3
// 500.240 us; speedup vs baseline: 5.1936x; 1.0502x over previous
//
#include <hip/hip_runtime.h>
#include <math.h>

#define BATCH 64
#define T 256
#define NF 64
#define H 128
#define H4 512                    // 4*H
#define HP1 129
#define WF_STRIDE (HP1 * H4)      // 66048 floats per feature
#define FEATS (NF * H + H)        // 8320
#define NTH 1024                  // scan kernel threads (16 waves)
#define PACK_UINT4_PER_F 8192     // 8 i * 1024 tid
#define PACK_BYTES (64u * PACK_UINT4_PER_F * 16u)   // 8 MB

typedef _Float16 half2_t __attribute__((ext_vector_type(2)));

__device__ __forceinline__ float sigmoidf_(float x) {
    return 1.0f / (1.0f + __expf(-x));
}

__device__ __forceinline__ float tanhf_(float x) {
    float ax = fabsf(x);
    float e = __expf(2.0f * ax);              // inf for large ax -> r = 1
    float r = 1.0f - 2.0f / (e + 1.0f);
    return copysignf(r, x);
}

__device__ __forceinline__ float fdot2_(half2_t a, half2_t b, float c) {
#if defined(__has_builtin)
#if __has_builtin(__builtin_amdgcn_fdot2)
    return __builtin_amdgcn_fdot2(a, b, c, false);
#else
    return fmaf((float)a.x, (float)b.x, fmaf((float)a.y, (float)b.y, c));
#endif
#else
    return fmaf((float)a.x, (float)b.x, fmaf((float)a.y, (float)b.y, c));
#endif
}

// ---------------- repack: W_lin rows 1..128 (h-part) -> fp16 blocked layout ----
// pack[(f*8 + i)*1024 + tid] = uint4 of 4 half2 for column c = tid&511,
// K-half kh = tid>>9, k0 = kh*64 + i*8:
//   h2[r] = ( W[f][1+k0+2r][c], W[f][2+k0+2r][c] ), r = 0..3
__global__ __launch_bounds__(256)
void repack_kernel(const float* __restrict__ W_lin, uint4* __restrict__ pack) {
    const int lin = blockIdx.x * 256 + threadIdx.x;      // 0..524287
    const int f   = lin >> 13;
    const int i   = (lin >> 10) & 7;
    const int tid = lin & 1023;
    const int kh  = tid >> 9;
    const int c   = tid & 511;
    const int k0  = kh * 64 + i * 8;
    const float* src = W_lin + (size_t)f * WF_STRIDE + (size_t)(1 + k0) * H4 + c;
    half2_t h[4];
    #pragma unroll
    for (int r = 0; r < 4; ++r) {
        h[r].x = (_Float16)src[(2 * r) * H4];
        h[r].y = (_Float16)src[(2 * r + 1) * H4];
    }
    pack[lin] = *(uint4*)h;
}

// ---------------- main scan kernel: 1024 threads, 8-uint4 double buffer ----
// Per-thread weight state: bufA[8]+bufB[8] = 64 VGPRs -> whole pipeline lives
// in VGPRs (no AGPR staging, no mid-step vmcnt drain). Each thread owns one
// gate column c = tid&511 and K-half kh = tid>>9.
__global__ __launch_bounds__(NTH, 4)
void lstm_scan_fp16_kernel(const float* __restrict__ X,
                           const int* __restrict__ lengths,
                           const float* __restrict__ W_lin,
                           const float* __restrict__ b_lin,
                           const float* __restrict__ W_dec,
                           const float* __restrict__ b_dec,
                           const float* __restrict__ W_out,
                           const float* __restrict__ b_out,
                           const uint4* __restrict__ pack,
                           float* __restrict__ out)
{
    __shared__ float s_feats[FEATS];          // [0,H)=c_t, [H,..)=h_t row-major
    __shared__ half2_t s_inp2[H / 2];         // decayed hidden row, fp16 pairs
    __shared__ float s_part[2][H4];           // K-half matvec partials
    __shared__ float s_X[4 * T];
    __shared__ float s_wdec[NF];
    __shared__ float s_bdec[NF];
    __shared__ float s_red[32];

    float* s_ct = s_feats;
    float* s_ht = s_feats + H;

    const int tid = threadIdx.x;
    const int b   = blockIdx.x;
    const int c   = tid & 511;                // gate column
    const int kh  = tid >> 9;                 // K half (0/1)

    const float* Xb = X + b * 4 * T;
    const int len = lengths[b];

    for (int i = tid; i < NF * H; i += NTH) s_ht[i] = 0.0f;
    for (int i = tid; i < 4 * T; i += NTH) s_X[i] = Xb[i];
    if (tid < NF) { s_wdec[tid] = W_dec[tid]; s_bdec[tid] = b_dec[tid]; }
    if (tid < H / 2) { half2_t z; z.x = (_Float16)0.0f; z.y = (_Float16)0.0f; s_inp2[tid] = z; }
    __syncthreads();

    float c_t = 0.0f, acc = 0.0f, cnt = 0.0f;

    uint4 bufA[8], bufB[8];
    float4 blA = make_float4(0.f, 0.f, 0.f, 0.f), blB = make_float4(0.f, 0.f, 0.f, 0.f);
    float  wxA = 0.0f, wxB = 0.0f;

    // prologue prefetch for step 0
    {
        const int m0 = (int)s_X[T];
        const uint4* Wp = pack + m0 * PACK_UINT4_PER_F + tid;
        #pragma unroll
        for (int i = 0; i < 8; ++i) bufA[i] = Wp[i * NTH];
        if (tid < H) {
            const float* bb = b_lin + m0 * H4 + tid;
            blA.x = bb[0]; blA.y = bb[H]; blA.z = bb[2 * H]; blA.w = bb[3 * H];
        }
        if (kh == 0) wxA = W_lin[(size_t)m0 * WF_STRIDE + c];
    }

    #define STEP(CURW, NXTW, CURB, NXTB, CURX, NXTX)                                \
    {                                                                               \
        const int   mj = (int)s_X[T + j];                                           \
        const float xj = s_X[2 * T + j];                                            \
        const int   jn = (j + 1 < T) ? (j + 1) : (T - 1);                           \
        const int   mjn = (int)s_X[T + jn];                                         \
        /* prefetch next step's weights / bias / x-row (consumed NEXT step) */      \
        {                                                                           \
            const uint4* Wp = pack + mjn * PACK_UINT4_PER_F + tid;                  \
            _Pragma("unroll")                                                       \
            for (int i = 0; i < 8; ++i) NXTW[i] = Wp[i * NTH];                      \
        }                                                                           \
        if (tid < H) {                                                              \
            const float* bb = b_lin + mjn * H4 + tid;                               \
            NXTB.x = bb[0]; NXTB.y = bb[H]; NXTB.z = bb[2 * H]; NXTB.w = bb[3 * H]; \
        }                                                                           \
        if (kh == 0) NXTX = W_lin[(size_t)mjn * WF_STRIDE + c];                     \
        /* matvec over registers preloaded LAST step */                             \
        float a0 = 0.0f, a1 = 0.0f;                                                 \
        _Pragma("unroll")                                                           \
        for (int i = 0; i < 8; ++i) {                                               \
            union { uint4 u; half2_t h[4]; } cv;                                    \
            cv.u = CURW[i];                                                         \
            const int ib = (kh << 5) + (i << 2);                                    \
            a0 = fdot2_(cv.h[0], s_inp2[ib],     a0);                               \
            a1 = fdot2_(cv.h[1], s_inp2[ib + 1], a1);                               \
            a0 = fdot2_(cv.h[2], s_inp2[ib + 2], a0);                               \
            a1 = fdot2_(cv.h[3], s_inp2[ib + 3], a1);                               \
        }                                                                           \
        float a = a0 + a1;                                                          \
        if (kh == 0) a = fmaf(xj, CURX, a);                                         \
        s_part[kh][c] = a;                                                          \
        __syncthreads();  /* B: partials ready */                                   \
        if (tid < H) {                                                              \
            const int h = tid;                                                      \
            const float gi = s_part[0][h]       + s_part[1][h]       + CURB.x;      \
            const float gf = s_part[0][H + h]   + s_part[1][H + h]   + CURB.y;      \
            const float go = s_part[0][2*H + h] + s_part[1][2*H + h] + CURB.z;      \
            const float gc = s_part[0][3*H + h] + s_part[1][3*H + h] + CURB.w;      \
            const float c_cand = sigmoidf_(gf) * c_t + sigmoidf_(gi) * tanhf_(gc);  \
            const float h_row  = sigmoidf_(go) * tanhf_(c_cand);                    \
            s_ht[mj * H + h] = h_row;                                               \
            acc += c_cand;                                                          \
            cnt += 1.0f;                                                            \
            const float tj = s_X[j];                                                \
            const float tn = (j < T - 1) ? s_X[j + 1] : (tj + 1.0f);                \
            const bool boundary = (j == len - 1) || (tn != tj);                     \
            if (boundary) { c_t = acc / fmaxf(cnt, 1.0f); acc = 0.0f; cnt = 0.0f; } \
            /* produce next step's decayed input (fp16) */                          \
            const float dn  = s_X[3 * T + jn];                                      \
            const float dmn = fmaf(s_wdec[mjn], dn, s_bdec[mjn]);                   \
            const float den = __expf(-fmaxf(0.0f, dmn));                            \
            const float hv  = (mjn == mj) ? h_row : s_ht[mjn * H + h];              \
            ((_Float16*)s_inp2)[h] = (_Float16)(den * hv);                          \
        }                                                                           \
        __syncthreads();  /* A: s_inp2 + h_t ready */                               \
    }

    int j = 0;
    while (j < len) {
        STEP(bufA, bufB, blA, blB, wxA, wxB); ++j;
        if (j >= len) break;
        STEP(bufB, bufA, blB, blA, wxB, wxA); ++j;
    }
    #undef STEP

    // ---- epilogue ----
    if (tid < H) s_ct[tid] = c_t;
    __syncthreads();

    float z0 = 0.0f, z1 = 0.0f;
    for (int i = tid; i < FEATS; i += NTH) {
        const float f = s_feats[i];
        const float2 w = *(const float2*)(W_out + 2 * i);
        z0 = fmaf(f, w.x, z0);
        z1 = fmaf(f, w.y, z1);
    }
    #pragma unroll
    for (int off = 32; off > 0; off >>= 1) {
        z0 += __shfl_down(z0, off, 64);
        z1 += __shfl_down(z1, off, 64);
    }
    const int wave = tid >> 6, lane = tid & 63;
    if (lane == 0) { s_red[2 * wave] = z0; s_red[2 * wave + 1] = z1; }
    __syncthreads();
    if (tid == 0) {
        float a0 = b_out[0], a1 = b_out[1];
        #pragma unroll
        for (int w = 0; w < 16; ++w) { a0 += s_red[2 * w]; a1 += s_red[2 * w + 1]; }
        const float mx = fmaxf(a0, a1);
        const float e0 = __expf(a0 - mx), e1 = __expf(a1 - mx);
        const float inv = 1.0f / (e0 + e1);
        out[2 * b]     = e0 * inv;
        out[2 * b + 1] = e1 * inv;
    }
}

// ---------------- fp32 fallback (no-workspace path) ----------------
#define NTHREADS 512
__global__ __launch_bounds__(NTHREADS)
void lstm_scan_kernel(const float* __restrict__ X,
                      const int* __restrict__ lengths,
                      const float* __restrict__ W_lin,
                      const float* __restrict__ b_lin,
                      const float* __restrict__ W_dec,
                      const float* __restrict__ b_dec,
                      const float* __restrict__ W_out,
                      const float* __restrict__ b_out,
                      float* __restrict__ out)
{
    __shared__ float s_feats[FEATS];
    __shared__ float s_inp[H];
    __shared__ float s_part[4][H4];
    __shared__ float s_X[4 * T];
    __shared__ float s_wdec[NF];
    __shared__ float s_bdec[NF];
    __shared__ float s_red[16];

    float* s_ct = s_feats;
    float* s_ht = s_feats + H;

    const int tid = threadIdx.x;
    const int b   = blockIdx.x;
    const int g4  = tid & 127;
    const int kq  = tid >> 7;

    const float* Xb = X + b * 4 * T;
    const int len = lengths[b];

    for (int i = tid; i < NF * H; i += NTHREADS) s_ht[i] = 0.0f;
    for (int i = tid; i < 4 * T; i += NTHREADS) s_X[i] = Xb[i];
    if (tid < NF) { s_wdec[tid] = W_dec[tid]; s_bdec[tid] = b_dec[tid]; }
    __syncthreads();

    float c_t = 0.0f, acc = 0.0f, cnt = 0.0f;

    for (int j = 0; j < len; ++j) {
        const int   mj = (int)s_X[T + j];
        const float xj = s_X[2 * T + j];
        const float* Wf = W_lin + mj * WF_STRIDE;

        float bl0, bl1, bl2, bl3;
        if (tid < H) {
            const float dj    = s_X[3 * T + j];
            const float dm    = fmaf(s_wdec[mj], dj, s_bdec[mj]);
            const float decay = __expf(-fmaxf(0.0f, dm));
            s_inp[tid] = decay * s_ht[mj * H + tid];
            const int m4 = mj * H4;
            bl0 = b_lin[m4 + tid];
            bl1 = b_lin[m4 + H + tid];
            bl2 = b_lin[m4 + 2 * H + tid];
            bl3 = b_lin[m4 + 3 * H + tid];
        }
        __syncthreads();

        float4 a4 = make_float4(0.0f, 0.0f, 0.0f, 0.0f);
        {
            const float*  wr  = Wf + (1 + kq * 32) * H4 + 4 * g4;
            const float4* ivp = (const float4*)(s_inp + kq * 32);
            #pragma unroll
            for (int c = 0; c < 8; ++c) {
                const float4 v = ivp[c];
                const float* wrc = wr + (4 * c) * H4;
                const float4 w0 = *(const float4*)(wrc);
                const float4 w1 = *(const float4*)(wrc + H4);
                const float4 w2 = *(const float4*)(wrc + 2 * H4);
                const float4 w3 = *(const float4*)(wrc + 3 * H4);
                a4.x = fmaf(v.x, w0.x, a4.x); a4.y = fmaf(v.x, w0.y, a4.y);
                a4.z = fmaf(v.x, w0.z, a4.z); a4.w = fmaf(v.x, w0.w, a4.w);
                a4.x = fmaf(v.y, w1.x, a4.x); a4.y = fmaf(v.y, w1.y, a4.y);
                a4.z = fmaf(v.y, w1.z, a4.z); a4.w = fmaf(v.y, w1.w, a4.w);
                a4.x = fmaf(v.z, w2.x, a4.x); a4.y = fmaf(v.z, w2.y, a4.y);
                a4.z = fmaf(v.z, w2.z, a4.z); a4.w = fmaf(v.z, w2.w, a4.w);
                a4.x = fmaf(v.w, w3.x, a4.x); a4.y = fmaf(v.w, w3.y, a4.y);
                a4.z = fmaf(v.w, w3.z, a4.z); a4.w = fmaf(v.w, w3.w, a4.w);
            }
        }
        if (kq == 0) {
            const float4 w = *(const float4*)(Wf + 4 * g4);
            a4.x = fmaf(xj, w.x, a4.x); a4.y = fmaf(xj, w.y, a4.y);
            a4.z = fmaf(xj, w.z, a4.z); a4.w = fmaf(xj, w.w, a4.w);
        }
        *(float4*)(&s_part[kq][4 * g4]) = a4;
        __syncthreads();

        if (tid < H) {
            const int h = tid;
            const float gi = s_part[0][h]         + s_part[1][h]         + s_part[2][h]         + s_part[3][h]         + bl0;
            const float gf = s_part[0][H + h]     + s_part[1][H + h]     + s_part[2][H + h]     + s_part[3][H + h]     + bl1;
            const float go = s_part[0][2*H + h]   + s_part[1][2*H + h]   + s_part[2][2*H + h]   + s_part[3][2*H + h]   + bl2;
            const float gc = s_part[0][3*H + h]   + s_part[1][3*H + h]   + s_part[2][3*H + h]   + s_part[3][3*H + h]   + bl3;

            const float c_cand = sigmoidf_(gf) * c_t + sigmoidf_(gi) * tanhf_(gc);
            const float h_row  = sigmoidf_(go) * tanhf_(c_cand);
            s_ht[mj * H + h] = h_row;
            acc += c_cand;
            cnt += 1.0f;

            const float tj = s_X[j];
            const float tn = (j < T - 1) ? s_X[j + 1] : (tj + 1.0f);
            const bool boundary = (j == len - 1) || (tn != tj);
            if (boundary) { c_t = acc / fmaxf(cnt, 1.0f); acc = 0.0f; cnt = 0.0f; }
        }
        __syncthreads();
    }

    if (tid < H) s_ct[tid] = c_t;
    __syncthreads();

    float z0 = 0.0f, z1 = 0.0f;
    for (int i = tid; i < FEATS; i += NTHREADS) {
        const float f = s_feats[i];
        const float2 w = *(const float2*)(W_out + 2 * i);
        z0 = fmaf(f, w.x, z0);
        z1 = fmaf(f, w.y, z1);
    }
    #pragma unroll
    for (int off = 32; off > 0; off >>= 1) {
        z0 += __shfl_down(z0, off, 64);
        z1 += __shfl_down(z1, off, 64);
    }
    const int wave = tid >> 6, lane = tid & 63;
    if (lane == 0) { s_red[2 * wave] = z0; s_red[2 * wave + 1] = z1; }
    __syncthreads();
    if (tid == 0) {
        float a0 = b_out[0], a1 = b_out[1];
        #pragma unroll
        for (int w = 0; w < 8; ++w) { a0 += s_red[2 * w]; a1 += s_red[2 * w + 1]; }
        const float mx = fmaxf(a0, a1);
        const float e0 = __expf(a0 - mx), e1 = __expf(a1 - mx);
        const float inv = 1.0f / (e0 + e1);
        out[2 * b]     = e0 * inv;
        out[2 * b + 1] = e1 * inv;
    }
}

extern "C" void kernel_launch(void* const* d_in, const int* in_sizes, int n_in,
                              void* d_out, int out_size, void* d_ws, size_t ws_size,
                              hipStream_t stream) {
    const float* X      = (const float*)d_in[0];
    const int*   lens   = (const int*)d_in[1];
    const float* W_lin  = (const float*)d_in[2];
    const float* b_lin  = (const float*)d_in[3];
    const float* W_dec  = (const float*)d_in[4];
    const float* b_dec  = (const float*)d_in[5];
    const float* W_out  = (const float*)d_in[6];
    const float* b_out  = (const float*)d_in[7];
    float* out = (float*)d_out;

    if (ws_size >= (size_t)PACK_BYTES) {
        uint4* pack = (uint4*)d_ws;
        hipLaunchKernelGGL(repack_kernel, dim3(2048), dim3(256), 0, stream, W_lin, pack);
        hipLaunchKernelGGL(lstm_scan_fp16_kernel, dim3(BATCH), dim3(NTH), 0, stream,
                           X, lens, W_lin, b_lin, W_dec, b_dec, W_out, b_out, pack, out);
    } else {
        hipLaunchKernelGGL(lstm_scan_kernel, dim3(BATCH), dim3(NTHREADS), 0, stream,
                           X, lens, W_lin, b_lin, W_dec, b_dec, W_out, b_out, out);
    }
}